// Round 4
// baseline (413.692 us; speedup 1.0000x reference)
//
#include <hip/hip_runtime.h>
#include <hip/hip_bf16.h>

// All inputs and the output are float32 (established rounds 0-3).
// R3 profile: split-K atomicAdd caused 8x HBM write amplification (24.6 MB vs 3 MB)
// -> all kernels now compute each output element exactly once; no memset needed.

__device__ __forceinline__ float leaky(float v) { return v >= 0.f ? v : 0.2f * v; }

struct GemmArgs {
    const float* W[4];
    const float* bias[4];
    int gstart[5];
    int in_roff[4];
    int rmul[4];
    int wstride[4];
};

// ---------- 32x32-tile GEMM for small layers (L1, L2); full-K loop, no atomics.
// 256 thr = 16 nq x 16 bq, thread 2x2. Optional fused prebias blocks (blockIdx.x >= nblk):
// re_bias[r,h] = rm_b1[r,h] + sum_d rank_emb[r,d] * rm_w1[r, 256+d, h]
template<bool IN_LEAKY, bool PRE>
__global__ __launch_bounds__(256, 2) void gemm32_kernel(
    const float* __restrict__ in, float* __restrict__ out,
    int K, int N, int nblk,
    const float* __restrict__ W, const float* __restrict__ bias,
    const float* __restrict__ rank_emb, const float* __restrict__ rm_w1,
    const float* __restrict__ rm_b1, float* __restrict__ re_bias)
{
    __shared__ __align__(16) float a_lds[64][34];
    __shared__ __align__(16) float w_lds[64][34];
    const int tid = threadIdx.x;
    if (PRE && (int)blockIdx.x >= nblk) {
        const int r = blockIdx.x - nblk;
        __shared__ float re[256];
        re[tid] = rank_emb[r * 256 + tid];
        __syncthreads();
        float acc = rm_b1[r * 256 + tid];
        const float* w = rm_w1 + ((size_t)r * 512 + 256) * 256 + tid;
        #pragma unroll 8
        for (int d = 0; d < 256; ++d) acc += re[d] * w[(size_t)d * 256];
        re_bias[r * 256 + tid] = acc;
        return;
    }
    const int bt = blockIdx.x & 1, nt = blockIdx.x >> 1;   // M=64 -> 2 b-tiles
    const int b0 = bt * 32, n0 = nt * 32;
    const int nq = tid & 15, bq = tid >> 4;
    float acc00, acc01, acc10, acc11;
    {
        float bv0 = bias[n0 + nq * 2], bv1 = bias[n0 + nq * 2 + 1];
        acc00 = bv0; acc01 = bv1; acc10 = bv0; acc11 = bv1;
    }
    for (int k0 = 0; k0 < K; k0 += 64) {
        #pragma unroll
        for (int j = 0; j < 8; ++j) {
            int idx = tid + j * 256;
            int k = idx & 63, c = idx >> 6;      // A: k fastest (coalesced on in)
            float v = in[(size_t)(b0 + c) * K + k0 + k];
            if (IN_LEAKY) v = leaky(v);
            a_lds[k][c] = v;
            int n = idx & 31, k2 = idx >> 5;     // W: n fastest (coalesced on W)
            w_lds[k2][n] = W[(size_t)(k0 + k2) * N + n0 + n];
        }
        __syncthreads();
        #pragma unroll 32
        for (int kk = 0; kk < 64; ++kk) {
            float2 a = *(const float2*)&a_lds[kk][bq * 2];
            float2 w = *(const float2*)&w_lds[kk][nq * 2];
            acc00 += a.x * w.x; acc01 += a.x * w.y;
            acc10 += a.y * w.x; acc11 += a.y * w.y;
        }
        __syncthreads();
    }
    out[(size_t)(b0 + bq * 2) * N + n0 + nq * 2]         = acc00;
    out[(size_t)(b0 + bq * 2) * N + n0 + nq * 2 + 1]     = acc01;
    out[(size_t)(b0 + bq * 2 + 1) * N + n0 + nq * 2]     = acc10;
    out[(size_t)(b0 + bq * 2 + 1) * N + n0 + nq * 2 + 1] = acc11;
}

// ---------- 64x64-tile batched-rank GEMM (L3, L4, G2); full-K, no atomics.
// out[b, y, n] = bias + sum_k in[b, r_in, k] * W[rw, k, n]
template<bool IN_LEAKY>
__global__ __launch_bounds__(256, 2) void gemm64_kernel(
    const float* __restrict__ in, float* __restrict__ out,
    int K, int N, int in_bs, int out_bs, int out_rs, GemmArgs ga)
{
    __shared__ __align__(16) float a_lds[64][72];   // [k][b]
    __shared__ __align__(16) float w_lds[64][72];   // [k][n]
    const int tid = threadIdx.x;
    const int nq = tid & 15, bq = tid >> 4;
    const int n0 = blockIdx.x * 64;
    const int y = blockIdx.y;
    int g = 0;
    while (g < 3 && y >= ga.gstart[g + 1]) ++g;
    const int rw = y - ga.gstart[g];
    const int r_in = ga.in_roff[g] + rw * ga.rmul[g];
    const float* Wp = ga.W[g] + (size_t)rw * ga.wstride[g];
    const size_t in_base = (size_t)r_in * K;

    float acc[4][4];
    #pragma unroll
    for (int j = 0; j < 4; ++j) {
        float bv = ga.bias[g][(size_t)rw * N + n0 + nq * 4 + j];
        #pragma unroll
        for (int i = 0; i < 4; ++i) acc[i][j] = bv;
    }
    for (int k0 = 0; k0 < K; k0 += 64) {
        #pragma unroll
        for (int j = 0; j < 16; ++j) {
            int idx = tid + j * 256;
            int k = idx & 63, b = idx >> 6;
            float v = in[(size_t)b * in_bs + in_base + k0 + k];
            if (IN_LEAKY) v = leaky(v);
            a_lds[k][b] = v;
        }
        #pragma unroll
        for (int j = 0; j < 16; ++j) {
            int idx = tid + j * 256;
            int n = idx & 63, k = idx >> 6;
            w_lds[k][n] = Wp[(size_t)(k0 + k) * N + n0 + n];
        }
        __syncthreads();
        #pragma unroll 16
        for (int kk = 0; kk < 64; ++kk) {
            float4 a = *(const float4*)&a_lds[kk][bq * 4];
            float4 w = *(const float4*)&w_lds[kk][nq * 4];
            float av[4] = {a.x, a.y, a.z, a.w};
            float wv[4] = {w.x, w.y, w.z, w.w};
            #pragma unroll
            for (int i = 0; i < 4; ++i)
                #pragma unroll
                for (int j = 0; j < 4; ++j)
                    acc[i][j] += av[i] * wv[j];
        }
        __syncthreads();
    }
    #pragma unroll
    for (int i = 0; i < 4; ++i) {
        int b = bq * 4 + i;
        float* op = out + (size_t)b * out_bs + (size_t)y * out_rs + n0 + nq * 4;
        float4 o; o.x = acc[i][0]; o.y = acc[i][1]; o.z = acc[i][2]; o.w = acc[i][3];
        *(float4*)op = o;
    }
}

// ---------- N=24 head output layer (K=256), block 128 = 8 nq x 16 bq; full-K, no atomics.
template<bool IN_LEAKY>
__global__ __launch_bounds__(128, 2) void gemm24_kernel(
    const float* __restrict__ in, float* __restrict__ out,
    int in_bs, GemmArgs ga)
{
    __shared__ __align__(16) float a_lds[64][72];
    __shared__ __align__(16) float w_lds[64][36];
    const int tid = threadIdx.x;
    const int nq = tid & 7, bq = tid >> 3;   // nq<6 valid (24 cols)
    const int y = blockIdx.y;
    int g = 0;
    while (g < 3 && y >= ga.gstart[g + 1]) ++g;
    const int rw = y - ga.gstart[g];
    const int r_in = ga.in_roff[g] + rw;
    const float* Wp = ga.W[g] + (size_t)rw * ga.wstride[g];

    float acc[4][4];
    #pragma unroll
    for (int j = 0; j < 4; ++j) {
        float bv = (nq < 6) ? ga.bias[g][(size_t)rw * 24 + nq * 4 + j] : 0.f;
        #pragma unroll
        for (int i = 0; i < 4; ++i) acc[i][j] = bv;
    }
    for (int k0 = 0; k0 < 256; k0 += 64) {
        #pragma unroll
        for (int j = 0; j < 32; ++j) {
            int idx = tid + j * 128;
            int k = idx & 63, b = idx >> 6;
            float v = in[(size_t)b * in_bs + (size_t)r_in * 256 + k0 + k];
            if (IN_LEAKY) v = leaky(v);
            a_lds[k][b] = v;
        }
        #pragma unroll
        for (int j = 0; j < 16; ++j) {
            int idx = tid + j * 128;
            int n = idx & 31, k = idx >> 5;
            w_lds[k][n] = (n < 24) ? Wp[(size_t)(k0 + k) * 24 + n] : 0.f;
        }
        __syncthreads();
        #pragma unroll 16
        for (int kk = 0; kk < 64; ++kk) {
            float4 a = *(const float4*)&a_lds[kk][bq * 4];
            float4 w = *(const float4*)&w_lds[kk][nq * 4];
            float av[4] = {a.x, a.y, a.z, a.w};
            float wv[4] = {w.x, w.y, w.z, w.w};
            #pragma unroll
            for (int i = 0; i < 4; ++i)
                #pragma unroll
                for (int j = 0; j < 4; ++j)
                    acc[i][j] += av[i] * wv[j];
        }
        __syncthreads();
    }
    if (nq < 6) {
        #pragma unroll
        for (int i = 0; i < 4; ++i) {
            int b = bq * 4 + i;
            float* op = out + (size_t)b * 1152 + y * 24 + nq * 4;
            #pragma unroll
            for (int j = 0; j < 4; ++j) op[j] = acc[i][j];
        }
    }
}

// ---------- fused spline + depth: block (w-tile, h-tile, b) recomputes its u/v/dx/dy
// slice from Pcat, then out[b,h,w] = sum_r u[r,w]*v[r,h] + dx[w] + dy[h]
// Pcat rows: [Px_m 0..15, Py_m 16..31, Px_a 32..39, Py_a 40..47]
__global__ __launch_bounds__(256, 2) void depth_fused_kernel(
    const float* __restrict__ Pcat,
    const float* __restrict__ mult_w, const float* __restrict__ addx_w,
    const float* __restrict__ addy_w, const float* __restrict__ gbias,
    float* __restrict__ out)
{
    __shared__ float cp[48][25];
    __shared__ float sw[33];
    __shared__ __align__(16) float u_s[16][132];
    __shared__ __align__(16) float v_s[16][132];
    __shared__ float dx_s[128], dy_s[128];
    const int tid = threadIdx.x;
    const int b = blockIdx.z, h0 = blockIdx.y * 128, w0 = blockIdx.x * 128;
    for (int idx = tid; idx < 1152; idx += 256)
        cp[idx / 24][idx % 24] = Pcat[(size_t)b * 1152 + idx];
    if (tid == 0) {
        float e[16], m, s;
        m = -1e30f; for (int i = 0; i < 16; ++i) m = fmaxf(m, mult_w[i]);
        s = 0.f;    for (int i = 0; i < 16; ++i) { e[i] = __expf(mult_w[i] - m); s += e[i]; }
        for (int i = 0; i < 16; ++i) sw[i] = e[i] / s;
        m = -1e30f; for (int i = 0; i < 8; ++i) m = fmaxf(m, addx_w[i]);
        s = 0.f;    for (int i = 0; i < 8; ++i) { e[i] = __expf(addx_w[i] - m); s += e[i]; }
        for (int i = 0; i < 8; ++i) sw[16 + i] = e[i] / s;
        m = -1e30f; for (int i = 0; i < 8; ++i) m = fmaxf(m, addy_w[i]);
        s = 0.f;    for (int i = 0; i < 8; ++i) { e[i] = __expf(addy_w[i] - m); s += e[i]; }
        for (int i = 0; i < 8; ++i) sw[24 + i] = e[i] / s;
        sw[32] = gbias[0];
    }
    __syncthreads();
    {   // spline phase: tid<128 -> w positions; tid>=128 -> h positions
        const int local = tid & 127;
        const int gpos = (tid < 128 ? w0 : h0) + local;
        const float eps = 0.001f;
        float t = eps + (float)gpos * ((1.f - 2.f * eps) / 511.f);
        float ts = t * 23.f;
        int seg = (int)ts; if (seg > 22) seg = 22;
        float tau = ts - (float)seg;
        tau = fminf(fmaxf(tau, 0.f), 0.9999f);
        float t2 = tau * tau, t3 = t2 * tau;
        float h00 = 2.f * t3 - 3.f * t2 + 1.f;
        float h10 = t3 - 2.f * t2 + tau;
        float h01 = -2.f * t3 + 3.f * t2;
        float h11 = t3 - t2;
        int sm1 = seg > 0 ? seg - 1 : 0;
        int s1 = seg + 1;
        int sp2 = s1 < 23 ? s1 + 1 : 23;
        const float msc = 0.5f / 23.f;
        auto spl = [&](int row) -> float {
            float pk = cp[row][seg], pk1 = cp[row][s1];
            float mk  = msc * (pk1 - cp[row][sm1]);
            float mk1 = msc * (cp[row][sp2] - pk);
            return h00 * pk + h10 * mk + h01 * pk1 + h11 * mk1;
        };
        if (tid < 128) {
            #pragma unroll
            for (int r = 0; r < 16; ++r) u_s[r][local] = sw[r] * spl(r);
            float dx = sw[32];
            #pragma unroll
            for (int r = 0; r < 8; ++r) dx += sw[16 + r] * spl(32 + r);
            dx_s[local] = dx;
        } else {
            #pragma unroll
            for (int r = 0; r < 16; ++r) v_s[r][local] = spl(16 + r);
            float dy = 0.f;
            #pragma unroll
            for (int r = 0; r < 8; ++r) dy += sw[24 + r] * spl(40 + r);
            dy_s[local] = dy;
        }
    }
    __syncthreads();
    const int tw = tid & 15, th = tid >> 4;
    float acc[8][8];
    #pragma unroll
    for (int i = 0; i < 8; ++i)
        #pragma unroll
        for (int j = 0; j < 8; ++j) acc[i][j] = 0.f;
    #pragma unroll
    for (int r = 0; r < 16; ++r) {
        float4 va0 = *(const float4*)&v_s[r][th * 8];
        float4 va1 = *(const float4*)&v_s[r][th * 8 + 4];
        float4 ub0 = *(const float4*)&u_s[r][tw * 8];
        float4 ub1 = *(const float4*)&u_s[r][tw * 8 + 4];
        float va[8] = {va0.x, va0.y, va0.z, va0.w, va1.x, va1.y, va1.z, va1.w};
        float ub[8] = {ub0.x, ub0.y, ub0.z, ub0.w, ub1.x, ub1.y, ub1.z, ub1.w};
        #pragma unroll
        for (int i = 0; i < 8; ++i)
            #pragma unroll
            for (int j = 0; j < 8; ++j)
                acc[i][j] += va[i] * ub[j];
    }
    #pragma unroll
    for (int i = 0; i < 8; ++i) {
        float dyh = dy_s[th * 8 + i];
        float* op = out + (size_t)b * 262144 + (size_t)(h0 + th * 8 + i) * 512 + w0 + tw * 8;
        float4 o0, o1;
        o0.x = acc[i][0] + dx_s[tw * 8 + 0] + dyh;
        o0.y = acc[i][1] + dx_s[tw * 8 + 1] + dyh;
        o0.z = acc[i][2] + dx_s[tw * 8 + 2] + dyh;
        o0.w = acc[i][3] + dx_s[tw * 8 + 3] + dyh;
        o1.x = acc[i][4] + dx_s[tw * 8 + 4] + dyh;
        o1.y = acc[i][5] + dx_s[tw * 8 + 5] + dyh;
        o1.z = acc[i][6] + dx_s[tw * 8 + 6] + dyh;
        o1.w = acc[i][7] + dx_s[tw * 8 + 7] + dyh;
        *(float4*)op = o0;
        *(float4*)(op + 4) = o1;
    }
}

// ---------- host ----------
extern "C" void kernel_launch(void* const* d_in, const int* in_sizes, int n_in,
                              void* d_out, int out_size, void* d_ws, size_t ws_size,
                              hipStream_t stream) {
    const float* in_h     = (const float*)d_in[0];
    const float* rank_emb = (const float*)d_in[1];
    const float* st_w1    = (const float*)d_in[2];
    const float* st_b1    = (const float*)d_in[3];
    const float* st_w2    = (const float*)d_in[4];
    const float* st_b2    = (const float*)d_in[5];
    const float* rm_w1    = (const float*)d_in[6];
    const float* rm_b1    = (const float*)d_in[7];
    const float* rm_w2    = (const float*)d_in[8];
    const float* rm_b2    = (const float*)d_in[9];
    const float* mx_w1    = (const float*)d_in[10];
    const float* mx_b1    = (const float*)d_in[11];
    const float* mx_w2    = (const float*)d_in[12];
    const float* mx_b2    = (const float*)d_in[13];
    const float* my_w1    = (const float*)d_in[14];
    const float* my_b1    = (const float*)d_in[15];
    const float* my_w2    = (const float*)d_in[16];
    const float* my_b2    = (const float*)d_in[17];
    const float* ax_w1    = (const float*)d_in[18];
    const float* ax_b1    = (const float*)d_in[19];
    const float* ax_w2    = (const float*)d_in[20];
    const float* ax_b2    = (const float*)d_in[21];
    const float* ay_w1    = (const float*)d_in[22];
    const float* ay_b1    = (const float*)d_in[23];
    const float* ay_w2    = (const float*)d_in[24];
    const float* ay_b2    = (const float*)d_in[25];
    const float* mult_w   = (const float*)d_in[26];
    const float* addx_w   = (const float*)d_in[27];
    const float* addy_w   = (const float*)d_in[28];
    const float* gbias    = (const float*)d_in[29];
    (void)in_sizes; (void)n_in; (void)out_size; (void)ws_size;

    float* ws      = (float*)d_ws;
    float* hid1    = ws;                 // 64x512
    float* shared_ = ws + 32768;         // 64x256
    float* re_bias = ws + 49152;         // 24x256
    float* rfh     = ws + 55296;         // 64x24x256
    float* rf      = ws + 448512;        // 64x24x256
    float* hcat    = ws + 841728;        // 64x48x256
    float* Pcat    = ws + 1628160;       // 64x48x24

    const int BIG = 1 << 30;

    // L1: h @ st_w1 + st_b1 -> hid1 (pre-act), K=768, N=512; 32 tiles + 24 fused prebias blocks
    gemm32_kernel<false, true><<<32 + 24, 256, 0, stream>>>(
        in_h, hid1, 768, 512, 32, st_w1, st_b1, rank_emb, rm_w1, rm_b1, re_bias);

    // L2: leaky(hid1) @ st_w2 + st_b2 -> shared_, K=512, N=256; 16 tiles
    gemm32_kernel<true, false><<<16, 256, 0, stream>>>(
        hid1, shared_, 512, 256, 16, st_w2, st_b2, nullptr, nullptr, nullptr, nullptr);

    {   // L3: shared_ @ rm_w1[:, :256, :] + re_bias -> rfh (pre-act), 24 ranks, K=256
        GemmArgs a{}; a.W[0] = rm_w1; a.bias[0] = re_bias;
        a.gstart[0] = 0; a.gstart[1] = BIG; a.gstart[2] = BIG; a.gstart[3] = BIG; a.gstart[4] = BIG;
        a.in_roff[0] = 0; a.rmul[0] = 0; a.wstride[0] = 512 * 256;
        gemm64_kernel<false><<<dim3(4, 24), 256, 0, stream>>>(
            shared_, rfh, 256, 256, 256, 6144, 256, a);
    }
    {   // L4: leaky(rfh) @ rm_w2 + rm_b2 -> rf, 24 ranks
        GemmArgs a{}; a.W[0] = rm_w2; a.bias[0] = rm_b2;
        a.gstart[0] = 0; a.gstart[1] = BIG; a.gstart[2] = BIG; a.gstart[3] = BIG; a.gstart[4] = BIG;
        a.in_roff[0] = 0; a.rmul[0] = 1; a.wstride[0] = 256 * 256;
        gemm64_kernel<true><<<dim3(4, 24), 256, 0, stream>>>(
            rfh, rf, 256, 256, 6144, 6144, 256, a);
    }
    {   // G2: rf -> hcat (pre-act hidden of 4 head groups), 48 rows
        GemmArgs a{};
        a.W[0] = mx_w1; a.W[1] = my_w1; a.W[2] = ax_w1; a.W[3] = ay_w1;
        a.bias[0] = mx_b1; a.bias[1] = my_b1; a.bias[2] = ax_b1; a.bias[3] = ay_b1;
        a.gstart[0] = 0; a.gstart[1] = 16; a.gstart[2] = 32; a.gstart[3] = 40; a.gstart[4] = 48;
        a.in_roff[0] = 0; a.in_roff[1] = 0; a.in_roff[2] = 16; a.in_roff[3] = 16;
        a.rmul[0] = 1; a.rmul[1] = 1; a.rmul[2] = 1; a.rmul[3] = 1;
        a.wstride[0] = 65536; a.wstride[1] = 65536; a.wstride[2] = 65536; a.wstride[3] = 65536;
        gemm64_kernel<false><<<dim3(4, 48), 256, 0, stream>>>(
            rf, hcat, 256, 256, 6144, 12288, 256, a);
    }
    {   // G3: leaky(hcat) -> Pcat (B,48,24)
        GemmArgs a{};
        a.W[0] = mx_w2; a.W[1] = my_w2; a.W[2] = ax_w2; a.W[3] = ay_w2;
        a.bias[0] = mx_b2; a.bias[1] = my_b2; a.bias[2] = ax_b2; a.bias[3] = ay_b2;
        a.gstart[0] = 0; a.gstart[1] = 16; a.gstart[2] = 32; a.gstart[3] = 40; a.gstart[4] = 48;
        a.in_roff[0] = 0; a.in_roff[1] = 16; a.in_roff[2] = 32; a.in_roff[3] = 40;
        a.rmul[0] = 1; a.rmul[1] = 1; a.rmul[2] = 1; a.rmul[3] = 1;
        a.wstride[0] = 6144; a.wstride[1] = 6144; a.wstride[2] = 6144; a.wstride[3] = 6144;
        gemm24_kernel<true><<<dim3(1, 48), 128, 0, stream>>>(hcat, Pcat, 12288, a);
    }
    // fused spline + depth
    depth_fused_kernel<<<dim3(4, 4, 64), 256, 0, stream>>>(
        Pcat, mult_w, addx_w, addy_w, gbias, (float*)d_out);
}